// Round 10
// baseline (95.288 us; speedup 1.0000x reference)
//
#include <hip/hip_runtime.h>
#include <hip/hip_bf16.h>
#include <math.h>

namespace {
constexpr int B = 8, N = 1024, F = 512, H = 4, D = 128, HD = H * D;
constexpr int ROWS = B * N;  // 8192
constexpr float LEAKY = 0.2f;

// ws layout (float slots):
constexpr size_t UV_OFF  = 0;        // [2][H][F] f32        = 4096
constexpr size_t ATT_OFF = 4096;     // [2][H][ROWS] f32     = 65536
constexpr size_t YT_OFF  = 69632;    // [HD][ROWS] bf16      = 2097152 slots
constexpr size_t XB_OFF  = 2166784;  // [ROWS][F] bf16       = 2097152 slots
constexpr size_t WKB_OFF = 4263936;  // [HD][F] bf16         = 131072 slots
}

typedef __attribute__((ext_vector_type(8))) short short8;
typedef __attribute__((ext_vector_type(4))) float f32x4;

__device__ __forceinline__ ushort bf16bits(float x) {
    __hip_bfloat16 h = __float2bfloat16(x);
    return *reinterpret_cast<ushort*>(&h);
}

// ---------------- kernel 1: fused uv + Wkb transpose -----------------------
extern "C" __global__ __launch_bounds__(256) void k_pre(
    const float* __restrict__ Watt, const float* __restrict__ aatt,
    const float* __restrict__ Wk, float* __restrict__ uv,
    __hip_bfloat16* __restrict__ Wkb) {
    __shared__ ushort T[128][136];
    if (blockIdx.x < 16) {
        int h = blockIdx.x >> 2, f0 = (blockIdx.x & 3) * 128;
#pragma unroll
        for (int p = 0; p < 16; ++p) {
            int fi = p * 8 + (threadIdx.x >> 5);
            int d4 = (threadIdx.x & 31) * 4;
            float4 v = *reinterpret_cast<const float4*>(
                Wk + ((size_t)h * F + f0 + fi) * D + d4);
            T[d4 + 0][fi] = bf16bits(v.x);
            T[d4 + 1][fi] = bf16bits(v.y);
            T[d4 + 2][fi] = bf16bits(v.z);
            T[d4 + 3][fi] = bf16bits(v.w);
        }
        __syncthreads();
        int d = threadIdx.x >> 1, hf = threadIdx.x & 1;
        ushort* dst =
            (ushort*)Wkb + (size_t)(h * 128 + d) * F + f0 + hf * 64;
        const ushort* src = &T[d][hf * 64];
#pragma unroll
        for (int q = 0; q < 8; ++q)
            *reinterpret_cast<uint4*>(dst + q * 8) =
                *reinterpret_cast<const uint4*>(src + q * 8);
    } else {
        int t = (blockIdx.x - 16) * 256 + threadIdx.x;  // [2][H][F]
        int f = t % F;
        int h = (t / F) % H;
        int w = t / (F * H);
        const float* Wrow = Watt + (size_t)(h * F + f) * D;
        const float* arow = aatt + (size_t)(h * 2 + w) * D;
        float s = 0.f;
#pragma unroll 4
        for (int d = 0; d < D; ++d) s = fmaf(Wrow[d], arow[d], s);
        uv[(size_t)w * (H * F) + h * F + f] = s;
    }
}

// ---------------- kernel 2: att scores + X->bf16 conversion ----------------
extern "C" __global__ __launch_bounds__(256) void k_att(
    const float* __restrict__ X, const float* __restrict__ uv,
    float* __restrict__ att, __hip_bfloat16* __restrict__ Xb) {
    int wave = threadIdx.x >> 6, lane = threadIdx.x & 63;
    int row = blockIdx.x * 4 + wave;  // b*N + n
    const float4* xr = reinterpret_cast<const float4*>(X + (size_t)row * F);
    float4 v0 = xr[lane * 2], v1 = xr[lane * 2 + 1];

    union { short8 s; ushort u[8]; } pk;
    pk.u[0] = bf16bits(v0.x); pk.u[1] = bf16bits(v0.y);
    pk.u[2] = bf16bits(v0.z); pk.u[3] = bf16bits(v0.w);
    pk.u[4] = bf16bits(v1.x); pk.u[5] = bf16bits(v1.y);
    pk.u[6] = bf16bits(v1.z); pk.u[7] = bf16bits(v1.w);
    *reinterpret_cast<short8*>(Xb + (size_t)row * F + lane * 8) = pk.s;

    float acc[2][H];
#pragma unroll
    for (int w = 0; w < 2; ++w)
#pragma unroll
        for (int h = 0; h < H; ++h) {
            const float4* up = reinterpret_cast<const float4*>(
                uv + (size_t)w * (H * F) + h * F + lane * 8);
            float4 u0 = up[0], u1 = up[1];
            float a = 0.f;
            a = fmaf(v0.x, u0.x, a); a = fmaf(v0.y, u0.y, a);
            a = fmaf(v0.z, u0.z, a); a = fmaf(v0.w, u0.w, a);
            a = fmaf(v1.x, u1.x, a); a = fmaf(v1.y, u1.y, a);
            a = fmaf(v1.z, u1.z, a); a = fmaf(v1.w, u1.w, a);
            acc[w][h] = a;
        }
#pragma unroll
    for (int w = 0; w < 2; ++w)
#pragma unroll
        for (int h = 0; h < H; ++h) {
            float v = acc[w][h];
#pragma unroll
            for (int off = 32; off > 0; off >>= 1) v += __shfl_xor(v, off);
            if (lane == 0) att[(size_t)w * (H * ROWS) + h * ROWS + row] = v;
        }
}

// ---------------- kernel 3: MFMA bf16 GEMM  Yt(bf16, transposed) -----------
// Yt[c][row] = sum_f Xb[row][f] * Wkb[c][f]; packed 4-row (8B) stores.
extern "C" __global__ __launch_bounds__(256) void k_gemm(
    const __hip_bfloat16* __restrict__ Xb,
    const __hip_bfloat16* __restrict__ Wkb,
    ushort* __restrict__ Yt) {
    __shared__ __align__(16) char smem[16384];  // A: [0,8K) B: [8K,16K)
    int tid = threadIdx.x;
    int lane = tid & 63, wv = tid >> 6;
    int wr = wv >> 1, wc = wv & 1;
    int lt = (blockIdx.x & 7) * 128 + (blockIdx.x >> 3);
    int bm = lt >> 3, bn = lt & 7;
    int row0 = bm * 64, col0 = bn * 64;

    const ushort* Ag = (const ushort*)Xb;
    const ushort* Bg = (const ushort*)Wkb;

    int aoff[2][2], boff[2][2];
#pragma unroll
    for (int ks = 0; ks < 2; ++ks) {
        int cb = ks * 4 + (lane >> 4);  // 16B chunk in K
#pragma unroll
        for (int i = 0; i < 2; ++i) {
            int ra = wr * 32 + i * 16 + (lane & 15);
            aoff[i][ks] = ra * 128 + (cb ^ (ra & 7)) * 16;
            int rb = wc * 32 + i * 16 + (lane & 15);
            boff[i][ks] = 8192 + rb * 128 + (cb ^ (rb & 7)) * 16;
        }
    }
    int srow[2], sgb[2];
#pragma unroll
    for (int i = 0; i < 2; ++i) {
        srow[i] = i * 32 + wv * 8 + (lane >> 3);
        sgb[i] = (lane & 7) ^ (srow[i] & 7);
    }

    f32x4 acc[2][2] = {};
    for (int k0 = 0; k0 < F; k0 += 64) {
        __syncthreads();
#pragma unroll
        for (int i = 0; i < 2; ++i) {
            const ushort* ga = Ag + (size_t)(row0 + srow[i]) * F + k0 + sgb[i] * 8;
            __builtin_amdgcn_global_load_lds(
                (const __attribute__((address_space(1))) uint32_t*)ga,
                (__attribute__((address_space(3))) uint32_t*)(smem + wv * 1024 + i * 4096),
                16, 0, 0);
            const ushort* gb = Bg + (size_t)(col0 + srow[i]) * F + k0 + sgb[i] * 8;
            __builtin_amdgcn_global_load_lds(
                (const __attribute__((address_space(1))) uint32_t*)gb,
                (__attribute__((address_space(3))) uint32_t*)(smem + 8192 + wv * 1024 + i * 4096),
                16, 0, 0);
        }
        __syncthreads();
#pragma unroll
        for (int ks = 0; ks < 2; ++ks) {
            short8 af[2], bf[2];
#pragma unroll
            for (int i = 0; i < 2; ++i) {
                af[i] = *reinterpret_cast<short8*>(smem + aoff[i][ks]);
                bf[i] = *reinterpret_cast<short8*>(smem + boff[i][ks]);
            }
#pragma unroll
            for (int mi = 0; mi < 2; ++mi)
#pragma unroll
                for (int ni = 0; ni < 2; ++ni)
                    acc[mi][ni] = __builtin_amdgcn_mfma_f32_16x16x32_bf16(
                        af[mi], bf[ni], acc[mi][ni], 0, 0, 0);
        }
    }
    int cr = (lane >> 4) * 4, cc = lane & 15;
#pragma unroll
    for (int mi = 0; mi < 2; ++mi)
#pragma unroll
        for (int ni = 0; ni < 2; ++ni) {
            int gr = row0 + wr * 32 + mi * 16 + cr;   // multiple of 4
            int gc = col0 + wc * 32 + ni * 16 + cc;
            ushort4 pk4 = make_ushort4(
                bf16bits(acc[mi][ni][0]), bf16bits(acc[mi][ni][1]),
                bf16bits(acc[mi][ni][2]), bf16bits(acc[mi][ni][3]));
            *reinterpret_cast<ushort4*>(Yt + (size_t)gc * ROWS + gr) = pk4;
        }
}

// ---------------- kernel 4: dense masked-softmax attention via MFMA --------
// 256 blocks = 8 batches x 32 row-tiles (batch->XCD). 4 waves = 4 heads.
// Bound-shift softmax (m = leaky(self + max_j neigh), exact by shift-inv);
// P fragments built in registers, B streamed from transposed Yt (L2-local).
extern "C" __global__ __launch_bounds__(256, 1) void k_attn_mfma(
    const float* __restrict__ A, const float* __restrict__ att,
    const ushort* __restrict__ Yt, const float* __restrict__ bias,
    float* __restrict__ out) {
    int g = blockIdx.x;
    int b = g & 7, it = g >> 3;     // batch -> XCD, 32 tiles per batch
    int i0 = it * 32;
    int bi0 = b * 1024 + i0;
    int tid = threadIdx.x, lane = tid & 63, w = tid >> 6;  // head = w
    int hs = lane >> 4, r15 = lane & 15;

    __shared__ float neighS[H][1024];   // 16KB
    __shared__ uint bitsS[32][33];      // padded: 4.2KB

    // stage neigh (head w) + nmax
    const float* nr = att + (size_t)(H + w) * ROWS + b * 1024;
    float nmax = -1e30f;
#pragma unroll
    for (int q = 0; q < 4; ++q) {
        float4 v = reinterpret_cast<const float4*>(nr)[lane + q * 64];
        *reinterpret_cast<float4*>(&neighS[w][(lane + q * 64) * 4]) = v;
        nmax = fmaxf(fmaxf(fmaxf(nmax, v.x), fmaxf(v.y, v.z)), v.w);
    }
#pragma unroll
    for (int off = 32; off > 0; off >>= 1)
        nmax = fmaxf(nmax, __shfl_xor(nmax, off));

    float sv = att[(size_t)w * ROWS + bi0 + (lane & 31)];
    float self0 = __shfl(sv, r15);
    float self1 = __shfl(sv, 16 + r15);
    float m0 = self0 + nmax; m0 = fmaxf(m0, LEAKY * m0);
    float m1 = self1 + nmax; m1 = fmaxf(m1, LEAKY * m1);

    // A -> bitmask (row = tid>>3, 128 cols per thread)
    {
        int row = tid >> 3, seg = tid & 7;
        const float4* ar = reinterpret_cast<const float4*>(
            A + (size_t)(bi0 + row) * 1024 + seg * 128);
        uint wb[4] = {0, 0, 0, 0};
#pragma unroll 4
        for (int q = 0; q < 32; ++q) {
            float4 v = ar[q];
            uint mk = (v.x != 0.f) | ((v.y != 0.f) << 1) |
                      ((v.z != 0.f) << 2) | ((v.w != 0.f) << 3);
            wb[q >> 3] |= mk << ((q & 7) * 4);
        }
#pragma unroll
        for (int q = 0; q < 4; ++q) bitsS[row][seg * 4 + q] = wb[q];
    }
    __syncthreads();

    // per-wave B column pointers (8 output col-fragments, head w)
    const ushort* colp[8];
#pragma unroll
    for (int ni = 0; ni < 8; ++ni)
        colp[ni] = Yt + (size_t)(w * 128 + ni * 16 + r15) * ROWS + b * 1024 +
                   hs * 8;

    f32x4 acc[2][8] = {};
    float lsum0 = 0.f, lsum1 = 0.f;

    for (int c = 0; c < 8; ++c) {       // K chunks of 128
        // issue kt=0 B loads early (latency hides under score VALU)
        short8 bf[8];
#pragma unroll
        for (int ni = 0; ni < 8; ++ni)
            bf[ni] = *reinterpret_cast<const short8*>(colp[ni] + c * 128);

        // build P fragments for this chunk (2 row-tiles x 4 k-tiles)
        short8 pa0[4], pa1[4];
#pragma unroll
        for (int kt = 0; kt < 4; ++kt) {
            int j0 = c * 128 + kt * 32 + hs * 8;
            float4 n0 = *reinterpret_cast<const float4*>(&neighS[w][j0]);
            float4 n1 = *reinterpret_cast<const float4*>(&neighS[w][j0 + 4]);
            float nj[8] = {n0.x, n0.y, n0.z, n0.w, n1.x, n1.y, n1.z, n1.w};
            uint by0 = (bitsS[r15][c * 4 + kt] >> (hs * 8)) & 0xffu;
            uint by1 = (bitsS[16 + r15][c * 4 + kt] >> (hs * 8)) & 0xffu;
            union { short8 s; ushort u[8]; } u0, u1;
#pragma unroll
            for (int q = 0; q < 8; ++q) {
                float s0 = self0 + nj[q]; s0 = fmaxf(s0, LEAKY * s0);
                float e0 = ((by0 >> q) & 1) ? __expf(s0 - m0) : 0.f;
                lsum0 += e0; u0.u[q] = bf16bits(e0);
                float s1 = self1 + nj[q]; s1 = fmaxf(s1, LEAKY * s1);
                float e1 = ((by1 >> q) & 1) ? __expf(s1 - m1) : 0.f;
                lsum1 += e1; u1.u[q] = bf16bits(e1);
            }
            pa0[kt] = u0.s; pa1[kt] = u1.s;
        }

        // MFMA with one-kt-ahead B prefetch
#pragma unroll
        for (int kt = 0; kt < 4; ++kt) {
            short8 bn[8];
            if (kt < 3) {
#pragma unroll
                for (int ni = 0; ni < 8; ++ni)
                    bn[ni] = *reinterpret_cast<const short8*>(
                        colp[ni] + c * 128 + (kt + 1) * 32);
            }
#pragma unroll
            for (int ni = 0; ni < 8; ++ni) {
                acc[0][ni] = __builtin_amdgcn_mfma_f32_16x16x32_bf16(
                    pa0[kt], bf[ni], acc[0][ni], 0, 0, 0);
                acc[1][ni] = __builtin_amdgcn_mfma_f32_16x16x32_bf16(
                    pa1[kt], bf[ni], acc[1][ni], 0, 0, 0);
            }
            if (kt < 3) {
#pragma unroll
                for (int ni = 0; ni < 8; ++ni) bf[ni] = bn[ni];
            }
        }
    }

    // row sums -> 1/l (every lane ends with sum for row r15 / 16+r15)
    lsum0 += __shfl_xor(lsum0, 16); lsum0 += __shfl_xor(lsum0, 32);
    lsum1 += __shfl_xor(lsum1, 16); lsum1 += __shfl_xor(lsum1, 32);
    float linv0 = 1.f / lsum0, linv1 = 1.f / lsum1;
    float li[2][4];
#pragma unroll
    for (int r = 0; r < 4; ++r) {
        li[0][r] = __shfl(linv0, hs * 4 + r);
        li[1][r] = __shfl(linv1, hs * 4 + r);
    }

    // epilogue: normalize + bias + ELU, C layout col=lane&15, row=hs*4+r
#pragma unroll
    for (int ni = 0; ni < 8; ++ni) {
        int col = w * 128 + ni * 16 + r15;
        float bv = bias[col];
#pragma unroll
        for (int rt = 0; rt < 2; ++rt)
#pragma unroll
            for (int r = 0; r < 4; ++r) {
                int rowc = rt * 16 + hs * 4 + r;
                float v = acc[rt][ni][r] * li[rt][r] + bv;
                v = v > 0.f ? v : expm1f(v);
                out[(size_t)(bi0 + rowc) * HD + col] = v;
            }
    }
}

extern "C" void kernel_launch(void* const* d_in, const int* in_sizes, int n_in,
                              void* d_out, int out_size, void* d_ws,
                              size_t ws_size, hipStream_t stream) {
    const float* X    = (const float*)d_in[0];
    const float* A    = (const float*)d_in[1];
    const float* Watt = (const float*)d_in[2];
    const float* aatt = (const float*)d_in[3];
    const float* Wk   = (const float*)d_in[4];
    const float* bias = (const float*)d_in[5];
    float* out = (float*)d_out;
    float* ws  = (float*)d_ws;

    float* uv  = ws + UV_OFF;
    float* att = ws + ATT_OFF;
    ushort* Yt = (ushort*)(ws + YT_OFF);
    __hip_bfloat16* Xb  = (__hip_bfloat16*)(ws + XB_OFF);
    __hip_bfloat16* Wkb = (__hip_bfloat16*)(ws + WKB_OFF);

    hipLaunchKernelGGL(k_pre, dim3(32), dim3(256), 0, stream, Watt, aatt, Wk,
                       uv, Wkb);
    hipLaunchKernelGGL(k_att, dim3(ROWS / 4), dim3(256), 0, stream, X, uv, att, Xb);
    hipLaunchKernelGGL(k_gemm, dim3((ROWS / 64) * (HD / 64)), dim3(256), 0,
                       stream, Xb, Wkb, Yt);
    hipLaunchKernelGGL(k_attn_mfma, dim3(256), dim3(256), 0, stream, A, att,
                       Yt, bias, out);
}

// Round 11
// 64.933 us; speedup vs baseline: 1.4675x; 1.4675x over previous
//
#include <hip/hip_runtime.h>
#include <hip/hip_bf16.h>
#include <math.h>

namespace {
constexpr int B = 8, N = 1024, F = 512, H = 4, D = 128, HD = H * D;
constexpr int ROWS = B * N;  // 8192
constexpr float LEAKY = 0.2f;

// ws layout (float slots):
constexpr size_t UV_OFF  = 0;        // [2][H][F] f32        = 4096
constexpr size_t ATT_OFF = 4096;     // [2][H][ROWS] f32     = 65536
constexpr size_t Y_OFF   = 69632;    // [ROWS][HD] bf16      = 2097152 slots
constexpr size_t XB_OFF  = 2166784;  // [ROWS][F] bf16       = 2097152 slots
constexpr size_t WKB_OFF = 4263936;  // [HD][F] bf16         = 131072 slots
}

typedef __attribute__((ext_vector_type(8))) short short8;
typedef __attribute__((ext_vector_type(4))) float f32x4;

__device__ __forceinline__ ushort bf16bits(float x) {
    __hip_bfloat16 h = __float2bfloat16(x);
    return *reinterpret_cast<ushort*>(&h);
}
__device__ __forceinline__ float blo(uint u) {
    return __uint_as_float(u << 16);
}
__device__ __forceinline__ float bhi(uint u) {
    return __uint_as_float(u & 0xffff0000u);
}

// ---------------- kernel 1: fused uv + Wkb transpose -----------------------
extern "C" __global__ __launch_bounds__(256) void k_pre(
    const float* __restrict__ Watt, const float* __restrict__ aatt,
    const float* __restrict__ Wk, float* __restrict__ uv,
    __hip_bfloat16* __restrict__ Wkb) {
    __shared__ ushort T[128][136];
    if (blockIdx.x < 16) {
        int h = blockIdx.x >> 2, f0 = (blockIdx.x & 3) * 128;
#pragma unroll
        for (int p = 0; p < 16; ++p) {
            int fi = p * 8 + (threadIdx.x >> 5);
            int d4 = (threadIdx.x & 31) * 4;
            float4 v = *reinterpret_cast<const float4*>(
                Wk + ((size_t)h * F + f0 + fi) * D + d4);
            T[d4 + 0][fi] = bf16bits(v.x);
            T[d4 + 1][fi] = bf16bits(v.y);
            T[d4 + 2][fi] = bf16bits(v.z);
            T[d4 + 3][fi] = bf16bits(v.w);
        }
        __syncthreads();
        int d = threadIdx.x >> 1, hf = threadIdx.x & 1;
        ushort* dst =
            (ushort*)Wkb + (size_t)(h * 128 + d) * F + f0 + hf * 64;
        const ushort* src = &T[d][hf * 64];
#pragma unroll
        for (int q = 0; q < 8; ++q)
            *reinterpret_cast<uint4*>(dst + q * 8) =
                *reinterpret_cast<const uint4*>(src + q * 8);
    } else {
        int t = (blockIdx.x - 16) * 256 + threadIdx.x;  // [2][H][F]
        int f = t % F;
        int h = (t / F) % H;
        int w = t / (F * H);
        const float* Wrow = Watt + (size_t)(h * F + f) * D;
        const float* arow = aatt + (size_t)(h * 2 + w) * D;
        float s = 0.f;
#pragma unroll 4
        for (int d = 0; d < D; ++d) s = fmaf(Wrow[d], arow[d], s);
        uv[(size_t)w * (H * F) + h * F + f] = s;
    }
}

// ---------------- kernel 2: att scores + X->bf16 conversion ----------------
extern "C" __global__ __launch_bounds__(256) void k_att(
    const float* __restrict__ X, const float* __restrict__ uv,
    float* __restrict__ att, __hip_bfloat16* __restrict__ Xb) {
    int wave = threadIdx.x >> 6, lane = threadIdx.x & 63;
    int row = blockIdx.x * 4 + wave;  // b*N + n
    const float4* xr = reinterpret_cast<const float4*>(X + (size_t)row * F);
    float4 v0 = xr[lane * 2], v1 = xr[lane * 2 + 1];

    union { short8 s; ushort u[8]; } pk;
    pk.u[0] = bf16bits(v0.x); pk.u[1] = bf16bits(v0.y);
    pk.u[2] = bf16bits(v0.z); pk.u[3] = bf16bits(v0.w);
    pk.u[4] = bf16bits(v1.x); pk.u[5] = bf16bits(v1.y);
    pk.u[6] = bf16bits(v1.z); pk.u[7] = bf16bits(v1.w);
    *reinterpret_cast<short8*>(Xb + (size_t)row * F + lane * 8) = pk.s;

    float acc[2][H];
#pragma unroll
    for (int w = 0; w < 2; ++w)
#pragma unroll
        for (int h = 0; h < H; ++h) {
            const float4* up = reinterpret_cast<const float4*>(
                uv + (size_t)w * (H * F) + h * F + lane * 8);
            float4 u0 = up[0], u1 = up[1];
            float a = 0.f;
            a = fmaf(v0.x, u0.x, a); a = fmaf(v0.y, u0.y, a);
            a = fmaf(v0.z, u0.z, a); a = fmaf(v0.w, u0.w, a);
            a = fmaf(v1.x, u1.x, a); a = fmaf(v1.y, u1.y, a);
            a = fmaf(v1.z, u1.z, a); a = fmaf(v1.w, u1.w, a);
            acc[w][h] = a;
        }
#pragma unroll
    for (int w = 0; w < 2; ++w)
#pragma unroll
        for (int h = 0; h < H; ++h) {
            float v = acc[w][h];
#pragma unroll
            for (int off = 32; off > 0; off >>= 1) v += __shfl_xor(v, off);
            if (lane == 0) att[(size_t)w * (H * ROWS) + h * ROWS + row] = v;
        }
}

// ---------------- kernel 3: MFMA bf16 GEMM  Y(bf16) = Xb @ Wkb^T -----------
// 128x64 tile (BK=64): halves tile-redundant traffic vs 64x64, grid 512
// (2 blocks/CU keeps inter-block latency hiding). Row-major Y output.
extern "C" __global__ __launch_bounds__(256) void k_gemm(
    const __hip_bfloat16* __restrict__ Xb,
    const __hip_bfloat16* __restrict__ Wkb,
    __hip_bfloat16* __restrict__ Y) {
    __shared__ __align__(16) char smem[24576];  // A: [0,16K) B: [16K,24K)
    int tid = threadIdx.x;
    int lane = tid & 63, wv = tid >> 6;
    int wr = wv >> 1, wc = wv & 1;        // wave quadrant: 64 rows x 32 cols
    // XCD swizzle: nwg=512 (%8==0)
    int lt = (blockIdx.x & 7) * 64 + (blockIdx.x >> 3);
    int bm = lt >> 3, bn = lt & 7;        // 64 x 8 tiles
    int row0 = bm * 128, col0 = bn * 64;

    const ushort* Ag = (const ushort*)Xb;
    const ushort* Bg = (const ushort*)Wkb;

    int aoff[4][2], boff[2][2];
#pragma unroll
    for (int ks = 0; ks < 2; ++ks) {
        int cb = ks * 4 + (lane >> 4);    // 16B chunk in K (0..7)
#pragma unroll
        for (int mi = 0; mi < 4; ++mi) {
            int ra = wr * 64 + mi * 16 + (lane & 15);
            aoff[mi][ks] = ra * 128 + (cb ^ (ra & 7)) * 16;
        }
#pragma unroll
        for (int ni = 0; ni < 2; ++ni) {
            int rb = wc * 32 + ni * 16 + (lane & 15);
            boff[ni][ks] = 16384 + rb * 128 + (cb ^ (rb & 7)) * 16;
        }
    }
    // staging: A ids 0..1023 (4 issues), B ids 0..511 (2 issues)
    int srowA[4], sgbA[4], srowB[2], sgbB[2];
#pragma unroll
    for (int i = 0; i < 4; ++i) {
        srowA[i] = i * 32 + wv * 8 + (lane >> 3);
        sgbA[i] = (lane & 7) ^ (srowA[i] & 7);
    }
#pragma unroll
    for (int i = 0; i < 2; ++i) {
        srowB[i] = i * 32 + wv * 8 + (lane >> 3);
        sgbB[i] = (lane & 7) ^ (srowB[i] & 7);
    }

    f32x4 acc[4][2] = {};
    for (int k0 = 0; k0 < F; k0 += 64) {
        __syncthreads();
#pragma unroll
        for (int i = 0; i < 4; ++i) {
            const ushort* ga = Ag + (size_t)(row0 + srowA[i]) * F + k0 + sgbA[i] * 8;
            __builtin_amdgcn_global_load_lds(
                (const __attribute__((address_space(1))) uint32_t*)ga,
                (__attribute__((address_space(3))) uint32_t*)(smem + i * 4096 + wv * 1024),
                16, 0, 0);
        }
#pragma unroll
        for (int i = 0; i < 2; ++i) {
            const ushort* gb = Bg + (size_t)(col0 + srowB[i]) * F + k0 + sgbB[i] * 8;
            __builtin_amdgcn_global_load_lds(
                (const __attribute__((address_space(1))) uint32_t*)gb,
                (__attribute__((address_space(3))) uint32_t*)(smem + 16384 + i * 4096 + wv * 1024),
                16, 0, 0);
        }
        __syncthreads();
#pragma unroll
        for (int ks = 0; ks < 2; ++ks) {
            short8 af[4], bf[2];
#pragma unroll
            for (int mi = 0; mi < 4; ++mi)
                af[mi] = *reinterpret_cast<short8*>(smem + aoff[mi][ks]);
#pragma unroll
            for (int ni = 0; ni < 2; ++ni)
                bf[ni] = *reinterpret_cast<short8*>(smem + boff[ni][ks]);
#pragma unroll
            for (int mi = 0; mi < 4; ++mi)
#pragma unroll
                for (int ni = 0; ni < 2; ++ni)
                    acc[mi][ni] = __builtin_amdgcn_mfma_f32_16x16x32_bf16(
                        af[mi], bf[ni], acc[mi][ni], 0, 0, 0);
        }
    }
    int cr = (lane >> 4) * 4, cc = lane & 15;
#pragma unroll
    for (int mi = 0; mi < 4; ++mi)
#pragma unroll
        for (int ni = 0; ni < 2; ++ni) {
            int gr = row0 + wr * 64 + mi * 16 + cr;
            int gc = col0 + wc * 32 + ni * 16 + cc;
#pragma unroll
            for (int r = 0; r < 4; ++r)
                Y[(size_t)(gr + r) * HD + gc] =
                    __float2bfloat16(acc[mi][ni][r]);
        }
}

// ---------------- kernel 4: sparse masked softmax + gather + bias + ELU ----
// R8 structure (proven 46.5us): one block per (b,i), batch->XCD affinity;
// one wave per head; 4-deep dwordx4 gather, VGPR < 56 band.
extern "C" __global__ __launch_bounds__(256) void k_attn_agg(
    const float* __restrict__ A, const float* __restrict__ att,
    const ushort* __restrict__ Y, const float* __restrict__ bias,
    float* __restrict__ out) {
    int g = blockIdx.x;
    int bi = ((g & 7) << 10) | (g >> 3);  // batch (g&7) -> XCD (g&7)
    int b = bi >> 10;
    int tid = threadIdx.x;
    int lane = tid & 63, wv = tid >> 6;
    __shared__ int idxs[N];
    __shared__ int2 ent[H][256];  // (byte-offset, score/weight bits) per head
    __shared__ int wsum[4];

    // Phase A: compact A-row to index list (wave shuffle scan, 2 barriers)
    const float* Arow = A + (size_t)bi * N;
    float4 av = *reinterpret_cast<const float4*>(Arow + tid * 4);
    int cnt = (av.x != 0.f) + (av.y != 0.f) + (av.z != 0.f) + (av.w != 0.f);
    int isc = cnt;
#pragma unroll
    for (int off = 1; off < 64; off <<= 1) {
        int t = __shfl_up(isc, off);
        if (lane >= off) isc += t;
    }
    if (lane == 63) wsum[wv] = isc;
    __syncthreads();
    int prefix = 0;
#pragma unroll
    for (int wj = 0; wj < 4; ++wj) prefix += (wj < wv) ? wsum[wj] : 0;
    int nnz = wsum[0] + wsum[1] + wsum[2] + wsum[3];
    int wo = prefix + isc - cnt;
    int jb = tid * 4;
    if (av.x != 0.f) idxs[wo++] = jb;
    if (av.y != 0.f) idxs[wo++] = jb + 1;
    if (av.z != 0.f) idxs[wo++] = jb + 2;
    if (av.w != 0.f) idxs[wo++] = jb + 3;
    __syncthreads();

    // Phase B: wave wv handles head h = wv. Barrier-free (private ent[h]).
    int h = wv;
    int grp = lane >> 4, sub = lane & 15;
    float sself = att[(size_t)h * ROWS + bi];
    const float* nrow = att + (size_t)(H + h) * ROWS + (size_t)b * N;
    const char* Ybyte = (const char*)(Y + ((size_t)b * N) * HD + h * D + sub * 8);

    float m = -1e30f, l = 0.f;
    float acc[8] = {};
    for (int c0 = 0; c0 < nnz; c0 += 256) {
        int cn = min(256, nnz - c0);
        int kpad = (cn + 15) & ~15;
        // pass 1: scores -> ent[h][k] (x = byte offset idx*HD*2), chunk max
        float lm = -1e30f;
        for (int k = lane; k < cn; k += 64) {
            int idx = idxs[c0 + k];
            float s = sself + nrow[idx];
            s = s >= 0.f ? s : LEAKY * s;
            ent[h][k] = make_int2(idx << 10, __float_as_int(s));
            lm = fmaxf(lm, s);
        }
        // zero-weight padding (offset 0, w 0): contributes nothing, valid loads
        for (int k = cn + lane; k < kpad; k += 64) ent[h][k] = make_int2(0, 0);
#pragma unroll
        for (int off = 32; off > 0; off >>= 1)
            lm = fmaxf(lm, __shfl_xor(lm, off));
        float mn = fmaxf(m, lm);
        float scale = __expf(m - mn);
        // pass 2: exp in place, chunk sum
        float ls = 0.f;
        for (int k = lane; k < cn; k += 64) {
            int2 p = ent[h][k];
            float e = __expf(__int_as_float(p.y) - mn);
            ent[h][k].y = __float_as_int(e);
            ls += e;
        }
#pragma unroll
        for (int off = 32; off > 0; off >>= 1) ls += __shfl_xor(ls, off);
        l = fmaf(l, scale, ls);
#pragma unroll
        for (int q = 0; q < 8; ++q) acc[q] *= scale;
        m = mn;
        // pass 3: gather, 16 neighbors/step; 4 loads in flight per lane
        for (int k = 0; k < kpad; k += 16) {
            int2 p[4];
#pragma unroll
            for (int q = 0; q < 4; ++q) p[q] = ent[h][k + q * 4 + grp];
            uint4 y[4];
#pragma unroll
            for (int q = 0; q < 4; ++q)
                y[q] = *reinterpret_cast<const uint4*>(Ybyte + (size_t)(uint)p[q].x);
#pragma unroll
            for (int q = 0; q < 4; ++q) {
                float w = __int_as_float(p[q].y);
                acc[0] = fmaf(w, blo(y[q].x), acc[0]);
                acc[1] = fmaf(w, bhi(y[q].x), acc[1]);
                acc[2] = fmaf(w, blo(y[q].y), acc[2]);
                acc[3] = fmaf(w, bhi(y[q].y), acc[3]);
                acc[4] = fmaf(w, blo(y[q].z), acc[4]);
                acc[5] = fmaf(w, bhi(y[q].z), acc[5]);
                acc[6] = fmaf(w, blo(y[q].w), acc[6]);
                acc[7] = fmaf(w, bhi(y[q].w), acc[7]);
            }
        }
    }
    // cross-group reduction (grp 0..3 hold disjoint neighbor subsets)
#pragma unroll
    for (int q = 0; q < 8; ++q) {
        acc[q] += __shfl_xor(acc[q], 16);
        acc[q] += __shfl_xor(acc[q], 32);
    }
    if (grp == 0) {
        float inv = 1.f / l;
        int cbase = h * D + sub * 8;
        float4 b0 = *reinterpret_cast<const float4*>(bias + cbase);
        float4 b1 = *reinterpret_cast<const float4*>(bias + cbase + 4);
        float o[8];
        o[0] = acc[0] * inv + b0.x; o[1] = acc[1] * inv + b0.y;
        o[2] = acc[2] * inv + b0.z; o[3] = acc[3] * inv + b0.w;
        o[4] = acc[4] * inv + b1.x; o[5] = acc[5] * inv + b1.y;
        o[6] = acc[6] * inv + b1.z; o[7] = acc[7] * inv + b1.w;
        // ELU: expf(v)-1 (abs err ~1e-7, vastly under threshold; expm1f is a
        // ~20-instr libcall)
#pragma unroll
        for (int q = 0; q < 8; ++q)
            o[q] = o[q] > 0.f ? o[q] : (__expf(o[q]) - 1.f);
        float* op = out + (size_t)bi * HD + cbase;
        *reinterpret_cast<float4*>(op) = make_float4(o[0], o[1], o[2], o[3]);
        *reinterpret_cast<float4*>(op + 4) = make_float4(o[4], o[5], o[6], o[7]);
    }
}

extern "C" void kernel_launch(void* const* d_in, const int* in_sizes, int n_in,
                              void* d_out, int out_size, void* d_ws,
                              size_t ws_size, hipStream_t stream) {
    const float* X    = (const float*)d_in[0];
    const float* A    = (const float*)d_in[1];
    const float* Watt = (const float*)d_in[2];
    const float* aatt = (const float*)d_in[3];
    const float* Wk   = (const float*)d_in[4];
    const float* bias = (const float*)d_in[5];
    float* out = (float*)d_out;
    float* ws  = (float*)d_ws;

    float* uv  = ws + UV_OFF;
    float* att = ws + ATT_OFF;
    __hip_bfloat16* Yb  = (__hip_bfloat16*)(ws + Y_OFF);
    __hip_bfloat16* Xb  = (__hip_bfloat16*)(ws + XB_OFF);
    __hip_bfloat16* Wkb = (__hip_bfloat16*)(ws + WKB_OFF);

    hipLaunchKernelGGL(k_pre, dim3(32), dim3(256), 0, stream, Watt, aatt, Wk,
                       uv, Wkb);
    hipLaunchKernelGGL(k_att, dim3(ROWS / 4), dim3(256), 0, stream, X, uv, att, Xb);
    hipLaunchKernelGGL(k_gemm, dim3((ROWS / 128) * (HD / 64)), dim3(256), 0,
                       stream, Xb, Wkb, Yb);
    hipLaunchKernelGGL(k_attn_agg, dim3(ROWS), dim3(256), 0, stream, A, att,
                       (const ushort*)Yb, bias, out);
}